// Round 1
// baseline (112.301 us; speedup 1.0000x reference)
//
#include <hip/hip_runtime.h>

// RoundRobinGate: output = (0.0 scalar, one-hot [2,4096,16,512] f32, same as bool).
// Fully input-independent constant tensor; pure write-bandwidth problem.
//
// Flat layout in d_out (float32 each):
//   p == 0                     -> 0.0f (scalar first output)
//   p in [1, 1+N1)             -> dense one-hot, j = p-1
//   p in [1+N1, 1+2*N1)        -> identical content (bool output as 1.0/0.0), j = p-1-N1
// For inner index j: row = j>>13 (8192 elems per (g,i) row), i = row & 4095,
// off = j & 8191, hot = ((i&15)<<9) | (i>>4)   [expert=i%16, cap slot=i/16, C=512]
// value = (off == hot) ? 1.0f : 0.0f

#define N1   67108864u          // 2*4096*16*512 elements per dense output
#define NTOT 134217729u         // 1 + 2*N1
#define NQ   33554432u          // float4 quads covering [0, NTOT-1)

__global__ void __launch_bounds__(256) rr_gate_fill(float4* __restrict__ out4,
                                                    float* __restrict__ out) {
    const unsigned stride = gridDim.x * blockDim.x;
    for (unsigned q = blockIdx.x * blockDim.x + threadIdx.x; q < NQ; q += stride) {
        const unsigned p0 = q << 2;
        float4 v;
        float vals[4];
#pragma unroll
        for (int k = 0; k < 4; ++k) {
            const unsigned p = p0 + (unsigned)k;
            float val = 0.0f;
            if (p >= 1u) {
                unsigned j = p - 1u;
                if (j >= N1) j -= N1;
                const unsigned off = j & 8191u;
                const unsigned i   = (j >> 13) & 4095u;
                const unsigned hot = ((i & 15u) << 9) | (i >> 4);
                val = (off == hot) ? 1.0f : 0.0f;
            }
            vals[k] = val;
        }
        v.x = vals[0]; v.y = vals[1]; v.z = vals[2]; v.w = vals[3];
        out4[q] = v;
    }
    // Final odd element (index NTOT-1): belongs to output2, i=4095 row, off=8191,
    // hot(4095) = (15<<9)|255 = 7935 != 8191 -> 0.0f
    if (blockIdx.x == 0 && threadIdx.x == 0) {
        out[NTOT - 1u] = 0.0f;
    }
}

extern "C" void kernel_launch(void* const* d_in, const int* in_sizes, int n_in,
                              void* d_out, int out_size, void* d_ws, size_t ws_size,
                              hipStream_t stream) {
    (void)d_in; (void)in_sizes; (void)n_in; (void)d_ws; (void)ws_size; (void)out_size;
    float* out = (float*)d_out;
    dim3 grid(2048), block(256);
    hipLaunchKernelGGL(rr_gate_fill, grid, block, 0, stream, (float4*)out, out);
}

// Round 2
// 93.421 us; speedup vs baseline: 1.2021x; 1.2021x over previous
//
#include <hip/hip_runtime.h>

// RoundRobinGate: output = (0.0 scalar, one-hot [2,4096,16,512] f32, same tensor as bool->f32).
// Fully input-independent. 537 MB of zeros + 16,384 ones.
//
// Strategy: hipMemsetAsync the whole output to 0 (rocclr fill path, ~6.8 TB/s measured
// on this harness's own poison fills), then scatter the 16,384 ones with a tiny kernel.
//
// Flat layout (float32): p=0 -> scalar 0.0; p in [1,1+N1) -> dense one-hot (j=p-1);
// p in [1+N1, 1+2N1) -> same content. For row i (0..4095), group g (0..1):
// hot column = expert*512 + cap = ((i&15)<<9)|(i>>4); row base = (g*4096+i)*8192.

#define N1   67108864u          // 2*4096*16*512 elements per dense output
#define NTOT 134217729u         // 1 + 2*N1

__global__ void __launch_bounds__(256) rr_gate_ones(float* __restrict__ out) {
    const unsigned tid = blockIdx.x * blockDim.x + threadIdx.x;   // [0, 16384)
    const unsigned i   = tid & 4095u;          // token row within group
    const unsigned g   = (tid >> 12) & 1u;     // group
    const unsigned t   = tid >> 13;            // which of the two identical outputs
    const unsigned hot = ((i & 15u) << 9) | (i >> 4);
    const unsigned p   = 1u + t * N1 + g * 33554432u + i * 8192u + hot;
    out[p] = 1.0f;
}

extern "C" void kernel_launch(void* const* d_in, const int* in_sizes, int n_in,
                              void* d_out, int out_size, void* d_ws, size_t ws_size,
                              hipStream_t stream) {
    (void)d_in; (void)in_sizes; (void)n_in; (void)d_ws; (void)ws_size; (void)out_size;
    float* out = (float*)d_out;
    // Zero the full output (scalar + both dense tensors), 536,870,916 bytes.
    hipMemsetAsync(d_out, 0, (size_t)NTOT * sizeof(float), stream);
    // Scatter the 16,384 ones: 2 outputs x 2 groups x 4096 rows.
    hipLaunchKernelGGL(rr_gate_ones, dim3(64), dim3(256), 0, stream, out);
}